// Round 6
// baseline (58.800 us; speedup 1.0000x reference)
//
#include <hip/hip_runtime.h>

// TMoELayer: B=4,T=4096 -> N=16384 tokens, D_IN=1024, D_OUT=1024, E=8, TOP_K=2, R=16
// out[n][o] = sum_k (gate(n,e)*ce[n][r]) * Bt[o][k], k = e*16+r
// Router logits via split-precision MFMA: W = Whi + Wlo/1024 (f16 pair),
// X = Xhi + Xlo (f16 pair) -> logit = Whi.Xhi + Whi.Xlo + (Wlo.Xhi + Wlo.Xlo)/1024.
constexpr float SCALING = 2.0f;  // alpha/r = 32/16

typedef __attribute__((ext_vector_type(8))) _Float16 half8;
typedef __attribute__((ext_vector_type(4))) _Float16 half4;
typedef __attribute__((ext_vector_type(4))) float    f32x4;

// ---------------- Kernel 0: prep
//  Bt[o][k]   = (f16) routed[e][o][r]                (256 KB)
//  A2[r][d]   = (f16)(2*compress[r][d])              (32 KB, 16 rows)
//  A1[j][d]   = (f16) w_route[j][d]          j<8
//  A1[j+8][d] = (f16)((w_route[j][d]-hi)*1024)       (32 KB, 16 rows)
__global__ __launch_bounds__(256) void k0_prep(
    const float* __restrict__ routed, const float* __restrict__ compress,
    const float* __restrict__ w_route, _Float16* __restrict__ Bt,
    _Float16* __restrict__ A1, _Float16* __restrict__ A2)
{
  const int bid = blockIdx.x, tid = threadIdx.x;
  if (bid < 32){
    const int t = bid * 256 + tid;            // 0..8191
    const int e = t & 7, o = t >> 3;
    const float4* rp = (const float4*)(routed + ((size_t)e * 1024 + o) * 16);
    float4 a = rp[0], b = rp[1], c = rp[2], d = rp[3];
    half8 h0, h1;
    h0[0]=(_Float16)a.x; h0[1]=(_Float16)a.y; h0[2]=(_Float16)a.z; h0[3]=(_Float16)a.w;
    h0[4]=(_Float16)b.x; h0[5]=(_Float16)b.y; h0[6]=(_Float16)b.z; h0[7]=(_Float16)b.w;
    h1[0]=(_Float16)c.x; h1[1]=(_Float16)c.y; h1[2]=(_Float16)c.z; h1[3]=(_Float16)c.w;
    h1[4]=(_Float16)d.x; h1[5]=(_Float16)d.y; h1[6]=(_Float16)d.z; h1[7]=(_Float16)d.w;
    _Float16* dst = Bt + (size_t)o * 128 + e * 16;
    *(half8*)(dst)     = h0;
    *(half8*)(dst + 8) = h1;
  } else if (bid < 40){
    const int t2 = (bid - 32) * 256 + tid;    // 0..2047, 8 f32 each
    const float4* cp = (const float4*)(compress) + (size_t)t2 * 2;
    float4 a = cp[0], b = cp[1];
    half8 h;
    h[0]=(_Float16)(SCALING*a.x); h[1]=(_Float16)(SCALING*a.y);
    h[2]=(_Float16)(SCALING*a.z); h[3]=(_Float16)(SCALING*a.w);
    h[4]=(_Float16)(SCALING*b.x); h[5]=(_Float16)(SCALING*b.y);
    h[6]=(_Float16)(SCALING*b.z); h[7]=(_Float16)(SCALING*b.w);
    *(half8*)(A2 + (size_t)t2 * 8) = h;
  } else {
    const int t3 = (bid - 40) * 256 + tid;    // 0..2047, 4 f32 of w_route each
    const int j = t3 >> 8, d = (t3 & 255) * 4;
    float4 w = ((const float4*)w_route)[t3];
    half4 hi, lo;
    hi[0]=(_Float16)w.x; hi[1]=(_Float16)w.y; hi[2]=(_Float16)w.z; hi[3]=(_Float16)w.w;
    lo[0]=(_Float16)((w.x-(float)hi[0])*1024.f);
    lo[1]=(_Float16)((w.y-(float)hi[1])*1024.f);
    lo[2]=(_Float16)((w.z-(float)hi[2])*1024.f);
    lo[3]=(_Float16)((w.w-(float)hi[3])*1024.f);
    *(half4*)(A1 + (size_t)j * 1024 + d)       = hi;
    *(half4*)(A1 + (size_t)(j + 8) * 1024 + d) = lo;
  }
}

// ---------------- Fused kernel: router+ce (phase A) then expert combine (phase B).
// Block = 16 tokens, 4 waves. Phase A: each wave one K-quarter, 3 MFMA streams,
// partials reduced through LDS, wave 0 writes ce (f16) + gate into LDS only.
// Phase B: 4 o-chunks of 256 (wave strip = 64 o); gated B-fragment built once per
// lane from LDS ce/gate, reused for all o-tiles; acc transposed through padded LDS
// so each global store instruction is one contiguous 1KB segment.
__global__ __launch_bounds__(256, 4) void k_fused(
    const float* __restrict__ x, const _Float16* __restrict__ A1,
    const _Float16* __restrict__ A2, const _Float16* __restrict__ Bt,
    float* __restrict__ out, int ntok)
{
  __shared__ float smem[16 * 260];          // 16.25 KB: phase-A p1/p2/p3 alias phase-B tile
  __shared__ _Float16 ce_lds[16][16];       // 512 B
  __shared__ float4   gate_lds[16];         // 256 B
  const int tid = threadIdx.x, lane = tid & 63, wv = tid >> 6;
  const int c15 = lane & 15, kg = lane >> 4;
  const int n0 = blockIdx.x * 16;

  f32x4* p1 = (f32x4*)(smem);               // [4][64]
  f32x4* p2 = (f32x4*)(smem + 1024);
  f32x4* p3 = (f32x4*)(smem + 2048);

  // ======== phase A: split-precision router + ce over this wave's K-quarter
  {
    const float*    xb  = x  + (size_t)(n0 + c15) * 1024 + wv * 256 + kg * 8;
    const _Float16* a1b = A1 + (size_t)c15 * 1024 + wv * 256 + kg * 8;
    const _Float16* a2b = A2 + (size_t)c15 * 1024 + wv * 256 + kg * 8;
    f32x4 acc1 = {0.f,0.f,0.f,0.f};   // [Whi;Wlo] * Xhi
    f32x4 acc3 = {0.f,0.f,0.f,0.f};   // [Whi;Wlo] * Xlo
    f32x4 acc2 = {0.f,0.f,0.f,0.f};   // (2*compress) * Xhi
    #pragma unroll
    for (int s = 0; s < 8; ++s){
      float4 xa = *(const float4*)(xb + s * 32);
      float4 xc = *(const float4*)(xb + s * 32 + 4);
      half8 a1 = *(const half8*)(a1b + s * 32);
      half8 a2 = *(const half8*)(a2b + s * 32);
      half8 bhi, blo;
      float xs[8] = {xa.x, xa.y, xa.z, xa.w, xc.x, xc.y, xc.z, xc.w};
      #pragma unroll
      for (int q = 0; q < 8; ++q){
        _Float16 h = (_Float16)xs[q];
        bhi[q] = h;
        blo[q] = (_Float16)(xs[q] - (float)h);
      }
      acc1 = __builtin_amdgcn_mfma_f32_16x16x32_f16(a1, bhi, acc1, 0, 0, 0);
      acc3 = __builtin_amdgcn_mfma_f32_16x16x32_f16(a1, blo, acc3, 0, 0, 0);
      acc2 = __builtin_amdgcn_mfma_f32_16x16x32_f16(a2, bhi, acc2, 0, 0, 0);
    }
    p1[wv * 64 + lane] = acc1;
    p3[wv * 64 + lane] = acc3;
    p2[wv * 64 + lane] = acc2;
  }
  __syncthreads();

  // ---- epilogue: wave 0 reduces partials, writes ce + gate to LDS
  if (wv == 0){
    f32x4 L = (p1[lane] + p1[64 + lane]) + (p1[128 + lane] + p1[192 + lane]);
    f32x4 X = (p3[lane] + p3[64 + lane]) + (p3[128 + lane] + p3[192 + lane]);
    f32x4 C = (p2[lane] + p2[64 + lane]) + (p2[128 + lane] + p2[192 + lane]);

    half4 hce;
    hce[0]=(_Float16)C[0]; hce[1]=(_Float16)C[1];
    hce[2]=(_Float16)C[2]; hce[3]=(_Float16)C[3];
    *(half4*)&ce_lds[c15][kg * 4] = hce;    // D row = r = kg*4+v, col = token = c15

    float lg[4];
    #pragma unroll
    for (int v = 0; v < 4; ++v){
      float wlo_xhi = __shfl_xor(L[v], 32, 64);
      float wlo_xlo = __shfl_xor(X[v], 32, 64);
      lg[v] = L[v] + X[v] + (wlo_xhi + wlo_xlo) * (1.0f / 1024.0f);
    }
    float l8[8];
    #pragma unroll
    for (int v = 0; v < 4; ++v){
      l8[v]     = lg[v];
      l8[4 + v] = __shfl_xor(lg[v], 16, 64);
    }
    if (lane < 16 && n0 + lane < ntok){
      float v0 = l8[0]; int e0 = 0;
      #pragma unroll
      for (int e = 1; e < 8; ++e) if (l8[e] > v0){ v0 = l8[e]; e0 = e; }
      float v1 = -3.402823466e38f; int e1 = 0;
      #pragma unroll
      for (int e = 0; e < 8; ++e) if (e != e0 && l8[e] > v1){ v1 = l8[e]; e1 = e; }
      float ex  = __expf(v1 - v0);
      float inv = 1.0f / (1.0f + ex);
      gate_lds[lane] = make_float4(__int_as_float(e0), __int_as_float(e1),
                                   inv, ex * inv);
    }
  }
  __syncthreads();

  // ======== phase B: out[16 tok][1024 o] = (gate⊙ce) @ Bt^T
  // B-fragment (gated ce) per lane, built once, reused across all 16 o-tiles
  half8 ce8 = *(const half8*)&ce_lds[c15][(kg & 1) * 8];
  float4 gt = gate_lds[c15];
  const int e0 = __float_as_int(gt.x), e1 = __float_as_int(gt.y);
  const int eb = kg >> 1;
  half8 bfr[4];
  #pragma unroll
  for (int s = 0; s < 4; ++s){
    const int e = 2 * s + eb;               // expert of k-range [s*32+kg*8, +8)
    float sc = (e == e0) ? gt.z : ((e == e1) ? gt.w : 0.f);
    _Float16 sh = (_Float16)sc;
    #pragma unroll
    for (int q = 0; q < 8; ++q) bfr[s][q] = ce8[q] * sh;
  }

  float (*t)[260] = (float(*)[260])smem;    // padded transpose tile (aliases p1/p2/p3)
  #pragma unroll
  for (int oc = 0; oc < 4; ++oc){
    const int o0w = oc * 256 + wv * 64;
    f32x4 acc[4] = {{0.f,0.f,0.f,0.f},{0.f,0.f,0.f,0.f},
                    {0.f,0.f,0.f,0.f},{0.f,0.f,0.f,0.f}};
    #pragma unroll
    for (int nc = 0; nc < 4; ++nc){
      #pragma unroll
      for (int s = 0; s < 4; ++s){
        half8 a = *(const half8*)(Bt + (size_t)(o0w + nc * 16 + c15) * 128
                                  + s * 32 + kg * 8);
        acc[nc] = __builtin_amdgcn_mfma_f32_16x16x32_f16(a, bfr[s], acc[nc], 0, 0, 0);
      }
    }
    // D[row = o-local = kg*4+v][col = token = c15] -> t[token][o-local]
    #pragma unroll
    for (int nc = 0; nc < 4; ++nc)
      *(f32x4*)&t[c15][wv * 64 + nc * 16 + kg * 4] = acc[nc];
    __syncthreads();
    // coalesced: wave wv stores rows {wv, wv+4, wv+8, wv+12}, 1KB contiguous each
    #pragma unroll
    for (int p = 0; p < 4; ++p){
      const int row = p * 4 + wv;
      float4 v = *(const float4*)&t[row][lane * 4];
      *(float4*)(out + (size_t)(n0 + row) * 1024 + oc * 256 + lane * 4) = v;
    }
    if (oc < 3) __syncthreads();
  }
}

extern "C" void kernel_launch(void* const* d_in, const int* in_sizes, int n_in,
                              void* d_out, int out_size, void* d_ws, size_t ws_size,
                              hipStream_t stream)
{
  const float* x        = (const float*)d_in[0];
  const float* w_route  = (const float*)d_in[1];
  const float* compress = (const float*)d_in[2];
  const float* routed   = (const float*)d_in[3];
  float* out = (float*)d_out;

  const int ntok = in_sizes[0] / 1024;   // 16384 (B*T)
  char* ws = (char*)d_ws;
  _Float16* Bt = (_Float16*)ws;                    // 1024*128 f16 (256 KB)
  _Float16* A1 = (_Float16*)(ws + 262144);         // 16*1024 f16  (32 KB)
  _Float16* A2 = (_Float16*)(ws + 262144 + 32768); // 16*1024 f16  (32 KB)

  k0_prep<<<48, 256, 0, stream>>>(routed, compress, w_route, Bt, A1, A2);
  k_fused<<<ntok / 16, 256, 0, stream>>>(x, A1, A2, Bt, out, ntok);
}

// Round 7
// 48.938 us; speedup vs baseline: 1.2015x; 1.2015x over previous
//
#include <hip/hip_runtime.h>

// TMoELayer: B=4,T=4096 -> N=16384 tokens, D_IN=1024, D_OUT=1024, E=8, TOP_K=2, R=16
// out[n][o] = sum_k (gate(n,e)*ce[n][r]) * Bt[o][k], k = e*16+r
// Router logits via split-precision MFMA: W = Whi + Wlo/1024 (f16 pair),
// X = Xhi + Xlo (f16 pair) -> logit = Whi.Xhi + Whi.Xlo + (Wlo.Xhi + Wlo.Xlo)/1024.
constexpr float SCALING = 2.0f;  // alpha/r = 32/16

typedef __attribute__((ext_vector_type(8))) _Float16 half8;
typedef __attribute__((ext_vector_type(4))) _Float16 half4;
typedef __attribute__((ext_vector_type(4))) float    f32x4;

// ---------------- Kernel 0: prep
//  Bt[o][k]   = (f16) routed[e][o][r]                (256 KB)
//  A2[r][d]   = (f16)(2*compress[r][d])              (32 KB, 16 rows)
//  A1[j][d]   = (f16) w_route[j][d]          j<8
//  A1[j+8][d] = (f16)((w_route[j][d]-hi)*1024)       (32 KB, 16 rows)
__global__ __launch_bounds__(256) void k0_prep(
    const float* __restrict__ routed, const float* __restrict__ compress,
    const float* __restrict__ w_route, _Float16* __restrict__ Bt,
    _Float16* __restrict__ A1, _Float16* __restrict__ A2)
{
  const int bid = blockIdx.x, tid = threadIdx.x;
  if (bid < 32){
    const int t = bid * 256 + tid;            // 0..8191
    const int e = t & 7, o = t >> 3;
    const float4* rp = (const float4*)(routed + ((size_t)e * 1024 + o) * 16);
    float4 a = rp[0], b = rp[1], c = rp[2], d = rp[3];
    half8 h0, h1;
    h0[0]=(_Float16)a.x; h0[1]=(_Float16)a.y; h0[2]=(_Float16)a.z; h0[3]=(_Float16)a.w;
    h0[4]=(_Float16)b.x; h0[5]=(_Float16)b.y; h0[6]=(_Float16)b.z; h0[7]=(_Float16)b.w;
    h1[0]=(_Float16)c.x; h1[1]=(_Float16)c.y; h1[2]=(_Float16)c.z; h1[3]=(_Float16)c.w;
    h1[4]=(_Float16)d.x; h1[5]=(_Float16)d.y; h1[6]=(_Float16)d.z; h1[7]=(_Float16)d.w;
    _Float16* dst = Bt + (size_t)o * 128 + e * 16;
    *(half8*)(dst)     = h0;
    *(half8*)(dst + 8) = h1;
  } else if (bid < 40){
    const int t2 = (bid - 32) * 256 + tid;    // 0..2047, 8 f32 each
    const float4* cp = (const float4*)(compress) + (size_t)t2 * 2;
    float4 a = cp[0], b = cp[1];
    half8 h;
    h[0]=(_Float16)(SCALING*a.x); h[1]=(_Float16)(SCALING*a.y);
    h[2]=(_Float16)(SCALING*a.z); h[3]=(_Float16)(SCALING*a.w);
    h[4]=(_Float16)(SCALING*b.x); h[5]=(_Float16)(SCALING*b.y);
    h[6]=(_Float16)(SCALING*b.z); h[7]=(_Float16)(SCALING*b.w);
    *(half8*)(A2 + (size_t)t2 * 8) = h;
  } else {
    const int t3 = (bid - 40) * 256 + tid;    // 0..2047, 4 f32 of w_route each
    const int j = t3 >> 8, d = (t3 & 255) * 4;
    float4 w = ((const float4*)w_route)[t3];
    half4 hi, lo;
    hi[0]=(_Float16)w.x; hi[1]=(_Float16)w.y; hi[2]=(_Float16)w.z; hi[3]=(_Float16)w.w;
    lo[0]=(_Float16)((w.x-(float)hi[0])*1024.f);
    lo[1]=(_Float16)((w.y-(float)hi[1])*1024.f);
    lo[2]=(_Float16)((w.z-(float)hi[2])*1024.f);
    lo[3]=(_Float16)((w.w-(float)hi[3])*1024.f);
    *(half4*)(A1 + (size_t)j * 1024 + d)       = hi;
    *(half4*)(A1 + (size_t)(j + 8) * 1024 + d) = lo;
  }
}

// ---------------- Kernel 1: all-MFMA router + ce. Block = 16 tokens, 4 waves
// (each wave one K-quarter). ALL 16 x-float4 loads hoisted before the MFMA loop
// so HBM/L3 latency is paid once per wave, not serially per step.
__global__ __launch_bounds__(256, 4) void k_main(
    const float* __restrict__ x, const _Float16* __restrict__ A1,
    const _Float16* __restrict__ A2, _Float16* __restrict__ ce16,
    float4* __restrict__ gate_ws, int ntok)
{
  __shared__ f32x4 p1[4][64], p2[4][64], p3[4][64];   // 12 KB
  const int tid = threadIdx.x, lane = tid & 63, wv = tid >> 6;
  const int c15 = lane & 15, kg = lane >> 4;
  const int n0 = blockIdx.x * 16;

  const float* xb = x + (size_t)(n0 + c15) * 1024 + wv * 256 + kg * 8;
  // hoist: 16 independent float4 loads in flight per lane (64 VGPR)
  float4 xv[8][2];
  #pragma unroll
  for (int s = 0; s < 8; ++s){
    xv[s][0] = *(const float4*)(xb + s * 32);
    xv[s][1] = *(const float4*)(xb + s * 32 + 4);
  }

  const _Float16* a1b = A1 + (size_t)c15 * 1024 + wv * 256 + kg * 8;
  const _Float16* a2b = A2 + (size_t)c15 * 1024 + wv * 256 + kg * 8;

  f32x4 acc1 = {0.f,0.f,0.f,0.f};   // [Whi;Wlo] * Xhi
  f32x4 acc3 = {0.f,0.f,0.f,0.f};   // [Whi;Wlo] * Xlo
  f32x4 acc2 = {0.f,0.f,0.f,0.f};   // (2*compress) * Xhi
  #pragma unroll
  for (int s = 0; s < 8; ++s){
    half8 a1 = *(const half8*)(a1b + s * 32);   // L2-resident (64 KB shared)
    half8 a2 = *(const half8*)(a2b + s * 32);
    half8 bhi, blo;
    float xs[8] = {xv[s][0].x, xv[s][0].y, xv[s][0].z, xv[s][0].w,
                   xv[s][1].x, xv[s][1].y, xv[s][1].z, xv[s][1].w};
    #pragma unroll
    for (int q = 0; q < 8; ++q){
      _Float16 h = (_Float16)xs[q];
      bhi[q] = h;
      blo[q] = (_Float16)(xs[q] - (float)h);
    }
    acc1 = __builtin_amdgcn_mfma_f32_16x16x32_f16(a1, bhi, acc1, 0, 0, 0);
    acc3 = __builtin_amdgcn_mfma_f32_16x16x32_f16(a1, blo, acc3, 0, 0, 0);
    acc2 = __builtin_amdgcn_mfma_f32_16x16x32_f16(a2, bhi, acc2, 0, 0, 0);
  }
  p1[wv][lane] = acc1;  p3[wv][lane] = acc3;  p2[wv][lane] = acc2;
  __syncthreads();
  if (wv != 0) return;

  f32x4 L = (p1[0][lane] + p1[1][lane]) + (p1[2][lane] + p1[3][lane]);
  f32x4 X = (p3[0][lane] + p3[1][lane]) + (p3[2][lane] + p3[3][lane]);
  f32x4 C = (p2[0][lane] + p2[1][lane]) + (p2[2][lane] + p2[3][lane]);

  // ce store: D row = r = kg*4+v, col = token = c15
  half4 hce;
  hce[0]=(_Float16)C[0]; hce[1]=(_Float16)C[1]; hce[2]=(_Float16)C[2]; hce[3]=(_Float16)C[3];
  *(half4*)(ce16 + (size_t)(n0 + c15) * 16 + kg * 4) = hce;

  // logits: rows 0..7 (kg 0/1) pick up Wlo terms from rows 8..15 (lane+32)
  float lg[4];
  #pragma unroll
  for (int v = 0; v < 4; ++v){
    float wlo_xhi = __shfl_xor(L[v], 32, 64);
    float wlo_xlo = __shfl_xor(X[v], 32, 64);
    lg[v] = L[v] + X[v] + (wlo_xhi + wlo_xlo) * (1.0f / 1024.0f);
  }
  float l8[8];
  #pragma unroll
  for (int v = 0; v < 4; ++v){
    l8[v]     = lg[v];
    l8[4 + v] = __shfl_xor(lg[v], 16, 64);
  }
  if (lane < 16 && n0 + lane < ntok){
    float v0 = l8[0]; int e0 = 0;
    #pragma unroll
    for (int e = 1; e < 8; ++e) if (l8[e] > v0){ v0 = l8[e]; e0 = e; }
    float v1 = -3.402823466e38f; int e1 = 0;
    #pragma unroll
    for (int e = 0; e < 8; ++e) if (e != e0 && l8[e] > v1){ v1 = l8[e]; e1 = e; }
    float ex  = __expf(v1 - v0);
    float inv = 1.0f / (1.0f + ex);
    gate_ws[n0 + lane] = make_float4(__int_as_float(e0), __int_as_float(e1),
                                     inv, ex * inv);
  }
}

// ---------------- Kernel 2: out = (gate⊙ce) @ Bt^T.
// Block = 64 tokens x 256 o (4 iters of 16 tokens). Bt register-resident across
// iters; ce/gate prefetched one iter ahead. Accumulators go through a
// DOUBLE-BUFFERED padded LDS tile: one barrier per iter, and the 1KB-contiguous
// global stores of iter i overlap the MFMAs of iter i+1.
__global__ __launch_bounds__(256, 4) void k2_gemm(
    const _Float16* __restrict__ Bt, const _Float16* __restrict__ ce16,
    const float4* __restrict__ gate_ws, float* __restrict__ out, int ntok)
{
  __shared__ float t[2][16][260];   // 32.5 KB, +4-word pad
  const int tid = threadIdx.x, lane = tid & 63, wv = tid >> 6;
  const int c15 = lane & 15, kg = lane >> 4;
  const int bn = blockIdx.x & 3;          // o-chunk of 256
  const int tg = blockIdx.x >> 2;         // token group of 64
  const int o0w = bn * 256 + wv * 64;

  // Bt fragments for this wave's 64 o x 128 k: 16 x half8 (64 VGPR), reused 4x
  half8 bt[4][4];
  #pragma unroll
  for (int nc = 0; nc < 4; ++nc)
    #pragma unroll
    for (int s = 0; s < 4; ++s)
      bt[nc][s] = *(const half8*)(Bt + (size_t)(o0w + nc * 16 + c15) * 128
                                  + s * 32 + kg * 8);

  int tok = tg * 64 + c15;
  half8  ce_n = *(const half8*)(ce16 + (size_t)tok * 16 + (kg & 1) * 8);
  float4 gt_n = gate_ws[tok];

  #pragma unroll
  for (int i = 0; i < 4; ++i){
    half8 ce_c = ce_n;  float4 gt_c = gt_n;
    if (i < 3){
      const int tok2 = tg * 64 + (i + 1) * 16 + c15;
      ce_n = *(const half8*)(ce16 + (size_t)tok2 * 16 + (kg & 1) * 8);
      gt_n = gate_ws[tok2];
    }
    const int e0 = __float_as_int(gt_c.x), e1 = __float_as_int(gt_c.y);
    const int eb = kg >> 1;

    f32x4 acc[4] = {{0.f,0.f,0.f,0.f},{0.f,0.f,0.f,0.f},
                    {0.f,0.f,0.f,0.f},{0.f,0.f,0.f,0.f}};
    #pragma unroll
    for (int s = 0; s < 4; ++s){
      const int e = 2 * s + eb;           // expert of k-range [s*32+kg*8, +8)
      float sc = (e == e0) ? gt_c.z : ((e == e1) ? gt_c.w : 0.f);
      _Float16 sh = (_Float16)sc;
      half8 bfr;
      #pragma unroll
      for (int q = 0; q < 8; ++q) bfr[q] = ce_c[q] * sh;
      #pragma unroll
      for (int nc = 0; nc < 4; ++nc)
        acc[nc] = __builtin_amdgcn_mfma_f32_16x16x32_f16(bt[nc][s], bfr, acc[nc], 0, 0, 0);
    }
    // D[row = o-local = kg*4+v][col = token = c15] -> t[buf][token][o-local]
    #pragma unroll
    for (int nc = 0; nc < 4; ++nc)
      *(f32x4*)&t[i & 1][c15][wv * 64 + nc * 16 + kg * 4] = acc[nc];
    __syncthreads();   // single barrier/iter: buf i&1 next written at iter i+2,
                       // which every wave reaches only after this barrier's
                       // successor -> reads below are race-free.
    const int n0i = tg * 64 + i * 16;
    #pragma unroll
    for (int p = 0; p < 4; ++p){
      const int row = p * 4 + wv;
      float4 v = *(const float4*)&t[i & 1][row][lane * 4];
      *(float4*)(out + (size_t)(n0i + row) * 1024 + bn * 256 + lane * 4) = v;
    }
  }
}

extern "C" void kernel_launch(void* const* d_in, const int* in_sizes, int n_in,
                              void* d_out, int out_size, void* d_ws, size_t ws_size,
                              hipStream_t stream)
{
  const float* x        = (const float*)d_in[0];
  const float* w_route  = (const float*)d_in[1];
  const float* compress = (const float*)d_in[2];
  const float* routed   = (const float*)d_in[3];
  float* out = (float*)d_out;

  const int ntok = in_sizes[0] / 1024;   // 16384 (B*T)
  char* ws = (char*)d_ws;
  _Float16* ce16    = (_Float16*)ws;                               // ntok*16 f16  (512 KB)
  float4*   gate_ws = (float4*)(ws + (size_t)ntok * 32);           // ntok*16 B    (256 KB)
  _Float16* Bt      = (_Float16*)(ws + (size_t)ntok * 48);         // 1024*128 f16 (256 KB)
  _Float16* A1      = (_Float16*)(ws + (size_t)ntok * 48 + 262144);          // 32 KB
  _Float16* A2      = (_Float16*)(ws + (size_t)ntok * 48 + 262144 + 32768);  // 32 KB

  k0_prep<<<48, 256, 0, stream>>>(routed, compress, w_route, Bt, A1, A2);
  k_main<<<ntok / 16, 256, 0, stream>>>(x, A1, A2, ce16, gate_ws, ntok);
  k2_gemm<<<(ntok / 64) * 4, 256, 0, stream>>>(Bt, ce16, gate_ws, out, ntok);
}

// Round 8
// 44.792 us; speedup vs baseline: 1.3127x; 1.0926x over previous
//
#include <hip/hip_runtime.h>

// TMoELayer: B=4,T=4096 -> N=16384 tokens, D_IN=1024, D_OUT=1024, E=8, TOP_K=2, R=16
// out[n][o] = sum_k (gate(n,e)*ce[n][r]) * routed[e][o][r], k = e*16+r
// Router logits via split-precision MFMA: W = Whi + Wlo/1024 (f16 pair),
// X = Xhi + Xlo (f16 pair) -> logit = Whi.Xhi + Whi.Xlo + (Wlo.Xhi + Wlo.Xlo)/1024.
// All operand tables are pre-layouted in FRAGMENT ORDER so every global load in the
// hot kernels is a contiguous 1KB wave-load (64 lanes x 16B), not 64 scattered pieces.
constexpr float SCALING = 2.0f;  // alpha/r = 32/16

typedef __attribute__((ext_vector_type(8))) _Float16 half8;
typedef __attribute__((ext_vector_type(4))) _Float16 half4;
typedef __attribute__((ext_vector_type(4))) float    f32x4;

// ---------------- Kernel 0: prep (fragment-order tables)
//  Btf[((ot*4+s)*64+l)*8+j] = (f16) routed[e][ot*16+(l&15)][r], ot=o-tile
//       where k = s*32 + (l>>4)*8 + j, e = k>>4, r = k&15          (256 KB)
//  A1f[((wq*8+s)*64+l)*8+j]: rows (l&15)<8 -> f16(w_route), else f16((w-hi)*1024)
//       cols wq*256+s*32+(l>>4)*8+j                                 (32 KB)
//  A2f same fragment order over f16(2*compress)                     (32 KB)
__global__ __launch_bounds__(256) void k0_prep(
    const float* __restrict__ routed, const float* __restrict__ compress,
    const float* __restrict__ w_route, _Float16* __restrict__ Btf,
    _Float16* __restrict__ A1f, _Float16* __restrict__ A2f)
{
  const int bid = blockIdx.x, tid = threadIdx.x;
  if (bid < 32){
    const int t = bid * 256 + tid;          // 0..8191, covers Btf idx pairs (2t,2t+1)
    const int l0  = (2 * t) & 63;           // even lane
    const int rem = (2 * t) >> 6;
    const int s = rem & 3, ot = rem >> 2;
    const int c15 = l0 & 15, kg = l0 >> 4;
    const int e  = 2 * s + (kg >> 1);
    const int r0 = (kg & 1) * 8;
    const float* src = routed + ((size_t)e * 1024 + ot * 16 + c15) * 16 + r0;
    float4 a = *(const float4*)(src);
    float4 b = *(const float4*)(src + 4);
    float4 c = *(const float4*)(src + 16);    // next o (c15+1)
    float4 d = *(const float4*)(src + 20);
    half8 h0, h1;
    h0[0]=(_Float16)a.x; h0[1]=(_Float16)a.y; h0[2]=(_Float16)a.z; h0[3]=(_Float16)a.w;
    h0[4]=(_Float16)b.x; h0[5]=(_Float16)b.y; h0[6]=(_Float16)b.z; h0[7]=(_Float16)b.w;
    h1[0]=(_Float16)c.x; h1[1]=(_Float16)c.y; h1[2]=(_Float16)c.z; h1[3]=(_Float16)c.w;
    h1[4]=(_Float16)d.x; h1[5]=(_Float16)d.y; h1[6]=(_Float16)d.z; h1[7]=(_Float16)d.w;
    *(half8*)(Btf + (size_t)t * 16)     = h0;
    *(half8*)(Btf + (size_t)t * 16 + 8) = h1;
  } else if (bid < 40){
    const int t2 = (bid - 32) * 256 + tid;  // 0..2047 -> A2f fragment t2
    const int l = t2 & 63, s = (t2 >> 6) & 7, wq = t2 >> 9;
    const int c15 = l & 15, kg = l >> 4;
    const float* src = compress + (size_t)c15 * 1024 + wq * 256 + s * 32 + kg * 8;
    float4 a = *(const float4*)(src);
    float4 b = *(const float4*)(src + 4);
    half8 h;
    h[0]=(_Float16)(SCALING*a.x); h[1]=(_Float16)(SCALING*a.y);
    h[2]=(_Float16)(SCALING*a.z); h[3]=(_Float16)(SCALING*a.w);
    h[4]=(_Float16)(SCALING*b.x); h[5]=(_Float16)(SCALING*b.y);
    h[6]=(_Float16)(SCALING*b.z); h[7]=(_Float16)(SCALING*b.w);
    *(half8*)(A2f + (size_t)t2 * 8) = h;
  } else {
    const int t3 = (bid - 40) * 256 + tid;  // 0..2047 -> A1f fragment t3
    const int l = t3 & 63, s = (t3 >> 6) & 7, wq = t3 >> 9;
    const int c15 = l & 15, kg = l >> 4;
    const int row = (c15 < 8) ? c15 : (c15 - 8);
    const float* src = w_route + (size_t)row * 1024 + wq * 256 + s * 32 + kg * 8;
    float4 a = *(const float4*)(src);
    float4 b = *(const float4*)(src + 4);
    float ws[8] = {a.x, a.y, a.z, a.w, b.x, b.y, b.z, b.w};
    half8 h;
    #pragma unroll
    for (int j = 0; j < 8; ++j){
      _Float16 hi = (_Float16)ws[j];
      h[j] = (c15 < 8) ? hi : (_Float16)((ws[j] - (float)hi) * 1024.f);
    }
    *(half8*)(A1f + (size_t)t3 * 8) = h;
  }
}

// ---------------- Kernel 1: all-MFMA router + ce. Block = 16 tokens, 4 waves.
// x staged COALESCED (lane->4 consecutive floats), converted to f16 hi/lo once,
// stored to padded LDS rows; MFMA B-fragments read back via ds_read_b128
// (2-way bank aliasing = free). A1f/A2f reads are contiguous 1KB wave-loads.
__global__ __launch_bounds__(256, 2) void k_main(
    const float* __restrict__ x, const _Float16* __restrict__ A1f,
    const _Float16* __restrict__ A2f, _Float16* __restrict__ ce16,
    float4* __restrict__ gate_ws, int ntok)
{
  __shared__ _Float16 xh[16 * 1032];        // 33 KB, row pitch 1032 halfs (+16B pad)
  __shared__ _Float16 xl[16 * 1032];        // 33 KB
  __shared__ f32x4 p1[4][64], p2[4][64], p3[4][64];   // 12 KB
  const int tid = threadIdx.x, lane = tid & 63, wv = tid >> 6;
  const int c15 = lane & 15, kg = lane >> 4;
  const int n0 = blockIdx.x * 16;

  // ---- stage: wave wv loads rows wv*4..+3 contiguously, cvt hi/lo, ds_write_b64
  float4 xv[16];
  #pragma unroll
  for (int u = 0; u < 16; ++u){
    const int rr = u >> 2, qt = u & 3;
    xv[u] = *(const float4*)(x + (size_t)(n0 + wv * 4 + rr) * 1024 + qt * 256 + lane * 4);
  }
  #pragma unroll
  for (int u = 0; u < 16; ++u){
    const int rr = u >> 2, qt = u & 3;
    float xs[4] = {xv[u].x, xv[u].y, xv[u].z, xv[u].w};
    half4 hi, lo;
    #pragma unroll
    for (int q = 0; q < 4; ++q){
      _Float16 h = (_Float16)xs[q];
      hi[q] = h;
      lo[q] = (_Float16)(xs[q] - (float)h);
    }
    const int ho = (wv * 4 + rr) * 1032 + qt * 256 + lane * 4;
    *(half4*)&xh[ho] = hi;
    *(half4*)&xl[ho] = lo;
  }
  __syncthreads();

  // ---- MFMA: wave wv does K-quarter wv. 3 streams x 8 steps.
  f32x4 acc1 = {0.f,0.f,0.f,0.f};   // [Whi;Wlo] * Xhi
  f32x4 acc3 = {0.f,0.f,0.f,0.f};   // [Whi;Wlo] * Xlo
  f32x4 acc2 = {0.f,0.f,0.f,0.f};   // (2*compress) * Xhi
  #pragma unroll
  for (int s = 0; s < 8; ++s){
    half8 a1 = *(const half8*)(A1f + ((size_t)(wv * 8 + s) * 64 + lane) * 8);
    half8 a2 = *(const half8*)(A2f + ((size_t)(wv * 8 + s) * 64 + lane) * 8);
    const int xo = c15 * 1032 + wv * 256 + s * 32 + kg * 8;
    half8 bhi = *(const half8*)&xh[xo];
    half8 blo = *(const half8*)&xl[xo];
    acc1 = __builtin_amdgcn_mfma_f32_16x16x32_f16(a1, bhi, acc1, 0, 0, 0);
    acc3 = __builtin_amdgcn_mfma_f32_16x16x32_f16(a1, blo, acc3, 0, 0, 0);
    acc2 = __builtin_amdgcn_mfma_f32_16x16x32_f16(a2, bhi, acc2, 0, 0, 0);
  }
  p1[wv][lane] = acc1;  p3[wv][lane] = acc3;  p2[wv][lane] = acc2;
  __syncthreads();
  if (wv != 0) return;

  f32x4 L = (p1[0][lane] + p1[1][lane]) + (p1[2][lane] + p1[3][lane]);
  f32x4 X = (p3[0][lane] + p3[1][lane]) + (p3[2][lane] + p3[3][lane]);
  f32x4 C = (p2[0][lane] + p2[1][lane]) + (p2[2][lane] + p2[3][lane]);

  // ce store: D row = r = kg*4+v, col = token = c15
  half4 hce;
  hce[0]=(_Float16)C[0]; hce[1]=(_Float16)C[1]; hce[2]=(_Float16)C[2]; hce[3]=(_Float16)C[3];
  *(half4*)(ce16 + (size_t)(n0 + c15) * 16 + kg * 4) = hce;

  // logits: rows 0..7 (kg 0/1) pick up Wlo terms from rows 8..15 (lane+32)
  float lg[4];
  #pragma unroll
  for (int v = 0; v < 4; ++v){
    float wlo_xhi = __shfl_xor(L[v], 32, 64);
    float wlo_xlo = __shfl_xor(X[v], 32, 64);
    lg[v] = L[v] + X[v] + (wlo_xhi + wlo_xlo) * (1.0f / 1024.0f);
  }
  float l8[8];
  #pragma unroll
  for (int v = 0; v < 4; ++v){
    l8[v]     = lg[v];
    l8[4 + v] = __shfl_xor(lg[v], 16, 64);
  }
  if (lane < 16 && n0 + lane < ntok){
    float v0 = l8[0]; int e0 = 0;
    #pragma unroll
    for (int e = 1; e < 8; ++e) if (l8[e] > v0){ v0 = l8[e]; e0 = e; }
    float v1 = -3.402823466e38f; int e1 = 0;
    #pragma unroll
    for (int e = 0; e < 8; ++e) if (e != e0 && l8[e] > v1){ v1 = l8[e]; e1 = e; }
    float ex  = __expf(v1 - v0);
    float inv = 1.0f / (1.0f + ex);
    gate_ws[n0 + lane] = make_float4(__int_as_float(e0), __int_as_float(e1),
                                     inv, ex * inv);
  }
}

// ---------------- Kernel 2: out = (gate⊙ce) @ Bt^T. ZERO barriers, zero LDS:
// stores stream freely (no vmcnt-drain points). Btf fragment loads coalesced,
// register-resident across 4 token-tiles; ce/gate prefetched one tile ahead.
__global__ __launch_bounds__(256, 4) void k2_gemm(
    const _Float16* __restrict__ Btf, const _Float16* __restrict__ ce16,
    const float4* __restrict__ gate_ws, float* __restrict__ out, int ntok)
{
  const int tid = threadIdx.x, lane = tid & 63, wv = tid >> 6;
  const int c15 = lane & 15, kg = lane >> 4;
  const int bn = blockIdx.x & 3;          // o-chunk of 256
  const int tg = blockIdx.x >> 2;         // token group of 64
  const int o0w = bn * 256 + wv * 64;

  // Btf fragments for this wave's 64 o x 128 k: 16 coalesced 1KB loads, reused 4x
  half8 bt[4][4];
  #pragma unroll
  for (int nc = 0; nc < 4; ++nc){
    const int ot = bn * 16 + wv * 4 + nc;
    #pragma unroll
    for (int s = 0; s < 4; ++s)
      bt[nc][s] = *(const half8*)(Btf + ((size_t)(ot * 4 + s) * 64 + lane) * 8);
  }

  int tok = tg * 64 + c15;
  half8  ce_n = *(const half8*)(ce16 + (size_t)tok * 16 + (kg & 1) * 8);
  float4 gt_n = gate_ws[tok];

  #pragma unroll
  for (int i = 0; i < 4; ++i){
    half8 ce_c = ce_n;  float4 gt_c = gt_n;
    if (i < 3){
      const int tok2 = tg * 64 + (i + 1) * 16 + c15;
      ce_n = *(const half8*)(ce16 + (size_t)tok2 * 16 + (kg & 1) * 8);
      gt_n = gate_ws[tok2];
    }
    const int e0 = __float_as_int(gt_c.x), e1 = __float_as_int(gt_c.y);
    const int eb = kg >> 1;

    f32x4 acc[4] = {{0.f,0.f,0.f,0.f},{0.f,0.f,0.f,0.f},
                    {0.f,0.f,0.f,0.f},{0.f,0.f,0.f,0.f}};
    #pragma unroll
    for (int s = 0; s < 4; ++s){
      const int e = 2 * s + eb;           // expert of k-range [s*32+kg*8, +8)
      float sc = (e == e0) ? gt_c.z : ((e == e1) ? gt_c.w : 0.f);
      _Float16 sh = (_Float16)sc;
      half8 bfr;
      #pragma unroll
      for (int q = 0; q < 8; ++q) bfr[q] = ce_c[q] * sh;
      #pragma unroll
      for (int nc = 0; nc < 4; ++nc)
        acc[nc] = __builtin_amdgcn_mfma_f32_16x16x32_f16(bt[nc][s], bfr, acc[nc], 0, 0, 0);
    }
    // D[row = o-local = kg*4+v][col = token = c15]: direct float4 store,
    // 16 rows x 64B segments per inst; nc loop covers full 256B per row.
    const int row = tg * 64 + i * 16 + c15;
    #pragma unroll
    for (int nc = 0; nc < 4; ++nc)
      *(float4*)(out + (size_t)row * 1024 + o0w + nc * 16 + kg * 4) =
          make_float4(acc[nc][0], acc[nc][1], acc[nc][2], acc[nc][3]);
  }
}

extern "C" void kernel_launch(void* const* d_in, const int* in_sizes, int n_in,
                              void* d_out, int out_size, void* d_ws, size_t ws_size,
                              hipStream_t stream)
{
  const float* x        = (const float*)d_in[0];
  const float* w_route  = (const float*)d_in[1];
  const float* compress = (const float*)d_in[2];
  const float* routed   = (const float*)d_in[3];
  float* out = (float*)d_out;

  const int ntok = in_sizes[0] / 1024;   // 16384 (B*T)
  char* ws = (char*)d_ws;
  _Float16* ce16    = (_Float16*)ws;                               // ntok*16 f16  (512 KB)
  float4*   gate_ws = (float4*)(ws + (size_t)ntok * 32);           // ntok*16 B    (256 KB)
  _Float16* Btf     = (_Float16*)(ws + (size_t)ntok * 48);         // 1024*128 f16 (256 KB)
  _Float16* A1f     = (_Float16*)(ws + (size_t)ntok * 48 + 262144);          // 32 KB
  _Float16* A2f     = (_Float16*)(ws + (size_t)ntok * 48 + 262144 + 32768);  // 32 KB

  k0_prep<<<48, 256, 0, stream>>>(routed, compress, w_route, Btf, A1f, A2f);
  k_main<<<ntok / 16, 256, 0, stream>>>(x, A1f, A2f, ce16, gate_ws, ntok);
  k2_gemm<<<(ntok / 64) * 4, 256, 0, stream>>>(Btf, ce16, gate_ws, out, ntok);
}

// Round 9
// 43.940 us; speedup vs baseline: 1.3382x; 1.0194x over previous
//
#include <hip/hip_runtime.h>

// TMoELayer: B=4,T=4096 -> N=16384 tokens, D_IN=1024, D_OUT=1024, E=8, TOP_K=2, R=16
// out[n][o] = sum_k (gate(n,e)*ce[n][r]) * routed[e][o][r], k = e*16+r
// Router logits via split-precision MFMA: W = Whi + Wlo/1024 (f16 pair),
// X = Xhi + Xlo (f16 pair) -> logit = Whi.Xhi + Whi.Xlo + (Wlo.Xhi + Wlo.Xlo)/1024.
// All operand tables are pre-layouted in FRAGMENT ORDER so every global load in the
// hot kernels is a contiguous 1KB wave-load (64 lanes x 16B), not 64 scattered pieces.
constexpr float SCALING = 2.0f;  // alpha/r = 32/16

typedef __attribute__((ext_vector_type(8))) _Float16 half8;
typedef __attribute__((ext_vector_type(4))) _Float16 half4;
typedef __attribute__((ext_vector_type(4))) float    f32x4;

// ---------------- Kernel 0: prep (fragment-order tables) — unchanged from R8
__global__ __launch_bounds__(256) void k0_prep(
    const float* __restrict__ routed, const float* __restrict__ compress,
    const float* __restrict__ w_route, _Float16* __restrict__ Btf,
    _Float16* __restrict__ A1f, _Float16* __restrict__ A2f)
{
  const int bid = blockIdx.x, tid = threadIdx.x;
  if (bid < 32){
    const int t = bid * 256 + tid;          // 0..8191, covers Btf idx pairs (2t,2t+1)
    const int l0  = (2 * t) & 63;           // even lane
    const int rem = (2 * t) >> 6;
    const int s = rem & 3, ot = rem >> 2;
    const int c15 = l0 & 15, kg = l0 >> 4;
    const int e  = 2 * s + (kg >> 1);
    const int r0 = (kg & 1) * 8;
    const float* src = routed + ((size_t)e * 1024 + ot * 16 + c15) * 16 + r0;
    float4 a = *(const float4*)(src);
    float4 b = *(const float4*)(src + 4);
    float4 c = *(const float4*)(src + 16);    // next o (c15+1)
    float4 d = *(const float4*)(src + 20);
    half8 h0, h1;
    h0[0]=(_Float16)a.x; h0[1]=(_Float16)a.y; h0[2]=(_Float16)a.z; h0[3]=(_Float16)a.w;
    h0[4]=(_Float16)b.x; h0[5]=(_Float16)b.y; h0[6]=(_Float16)b.z; h0[7]=(_Float16)b.w;
    h1[0]=(_Float16)c.x; h1[1]=(_Float16)c.y; h1[2]=(_Float16)c.z; h1[3]=(_Float16)c.w;
    h1[4]=(_Float16)d.x; h1[5]=(_Float16)d.y; h1[6]=(_Float16)d.z; h1[7]=(_Float16)d.w;
    *(half8*)(Btf + (size_t)t * 16)     = h0;
    *(half8*)(Btf + (size_t)t * 16 + 8) = h1;
  } else if (bid < 40){
    const int t2 = (bid - 32) * 256 + tid;  // 0..2047 -> A2f fragment t2
    const int l = t2 & 63, s = (t2 >> 6) & 7, wq = t2 >> 9;
    const int c15 = l & 15, kg = l >> 4;
    const float* src = compress + (size_t)c15 * 1024 + wq * 256 + s * 32 + kg * 8;
    float4 a = *(const float4*)(src);
    float4 b = *(const float4*)(src + 4);
    half8 h;
    h[0]=(_Float16)(SCALING*a.x); h[1]=(_Float16)(SCALING*a.y);
    h[2]=(_Float16)(SCALING*a.z); h[3]=(_Float16)(SCALING*a.w);
    h[4]=(_Float16)(SCALING*b.x); h[5]=(_Float16)(SCALING*b.y);
    h[6]=(_Float16)(SCALING*b.z); h[7]=(_Float16)(SCALING*b.w);
    *(half8*)(A2f + (size_t)t2 * 8) = h;
  } else {
    const int t3 = (bid - 40) * 256 + tid;  // 0..2047 -> A1f fragment t3
    const int l = t3 & 63, s = (t3 >> 6) & 7, wq = t3 >> 9;
    const int c15 = l & 15, kg = l >> 4;
    const int row = (c15 < 8) ? c15 : (c15 - 8);
    const float* src = w_route + (size_t)row * 1024 + wq * 256 + s * 32 + kg * 8;
    float4 a = *(const float4*)(src);
    float4 b = *(const float4*)(src + 4);
    float ws[8] = {a.x, a.y, a.z, a.w, b.x, b.y, b.z, b.w};
    half8 h;
    #pragma unroll
    for (int j = 0; j < 8; ++j){
      _Float16 hi = (_Float16)ws[j];
      h[j] = (c15 < 8) ? hi : (_Float16)((ws[j] - (float)hi) * 1024.f);
    }
    *(half8*)(A1f + (size_t)t3 * 8) = h;
  }
}

// ---------------- Kernel 1: all-MFMA router + ce — unchanged from R8
__global__ __launch_bounds__(256, 2) void k_main(
    const float* __restrict__ x, const _Float16* __restrict__ A1f,
    const _Float16* __restrict__ A2f, _Float16* __restrict__ ce16,
    float4* __restrict__ gate_ws, int ntok)
{
  __shared__ _Float16 xh[16 * 1032];        // 33 KB, row pitch 1032 halfs (+16B pad)
  __shared__ _Float16 xl[16 * 1032];        // 33 KB
  __shared__ f32x4 p1[4][64], p2[4][64], p3[4][64];   // 12 KB
  const int tid = threadIdx.x, lane = tid & 63, wv = tid >> 6;
  const int c15 = lane & 15, kg = lane >> 4;
  const int n0 = blockIdx.x * 16;

  float4 xv[16];
  #pragma unroll
  for (int u = 0; u < 16; ++u){
    const int rr = u >> 2, qt = u & 3;
    xv[u] = *(const float4*)(x + (size_t)(n0 + wv * 4 + rr) * 1024 + qt * 256 + lane * 4);
  }
  #pragma unroll
  for (int u = 0; u < 16; ++u){
    const int rr = u >> 2, qt = u & 3;
    float xs[4] = {xv[u].x, xv[u].y, xv[u].z, xv[u].w};
    half4 hi, lo;
    #pragma unroll
    for (int q = 0; q < 4; ++q){
      _Float16 h = (_Float16)xs[q];
      hi[q] = h;
      lo[q] = (_Float16)(xs[q] - (float)h);
    }
    const int ho = (wv * 4 + rr) * 1032 + qt * 256 + lane * 4;
    *(half4*)&xh[ho] = hi;
    *(half4*)&xl[ho] = lo;
  }
  __syncthreads();

  f32x4 acc1 = {0.f,0.f,0.f,0.f};   // [Whi;Wlo] * Xhi
  f32x4 acc3 = {0.f,0.f,0.f,0.f};   // [Whi;Wlo] * Xlo
  f32x4 acc2 = {0.f,0.f,0.f,0.f};   // (2*compress) * Xhi
  #pragma unroll
  for (int s = 0; s < 8; ++s){
    half8 a1 = *(const half8*)(A1f + ((size_t)(wv * 8 + s) * 64 + lane) * 8);
    half8 a2 = *(const half8*)(A2f + ((size_t)(wv * 8 + s) * 64 + lane) * 8);
    const int xo = c15 * 1032 + wv * 256 + s * 32 + kg * 8;
    half8 bhi = *(const half8*)&xh[xo];
    half8 blo = *(const half8*)&xl[xo];
    acc1 = __builtin_amdgcn_mfma_f32_16x16x32_f16(a1, bhi, acc1, 0, 0, 0);
    acc3 = __builtin_amdgcn_mfma_f32_16x16x32_f16(a1, blo, acc3, 0, 0, 0);
    acc2 = __builtin_amdgcn_mfma_f32_16x16x32_f16(a2, bhi, acc2, 0, 0, 0);
  }
  p1[wv][lane] = acc1;  p3[wv][lane] = acc3;  p2[wv][lane] = acc2;
  __syncthreads();
  if (wv != 0) return;

  f32x4 L = (p1[0][lane] + p1[1][lane]) + (p1[2][lane] + p1[3][lane]);
  f32x4 X = (p3[0][lane] + p3[1][lane]) + (p3[2][lane] + p3[3][lane]);
  f32x4 C = (p2[0][lane] + p2[1][lane]) + (p2[2][lane] + p2[3][lane]);

  half4 hce;
  hce[0]=(_Float16)C[0]; hce[1]=(_Float16)C[1]; hce[2]=(_Float16)C[2]; hce[3]=(_Float16)C[3];
  *(half4*)(ce16 + (size_t)(n0 + c15) * 16 + kg * 4) = hce;

  float lg[4];
  #pragma unroll
  for (int v = 0; v < 4; ++v){
    float wlo_xhi = __shfl_xor(L[v], 32, 64);
    float wlo_xlo = __shfl_xor(X[v], 32, 64);
    lg[v] = L[v] + X[v] + (wlo_xhi + wlo_xlo) * (1.0f / 1024.0f);
  }
  float l8[8];
  #pragma unroll
  for (int v = 0; v < 4; ++v){
    l8[v]     = lg[v];
    l8[4 + v] = __shfl_xor(lg[v], 16, 64);
  }
  if (lane < 16 && n0 + lane < ntok){
    float v0 = l8[0]; int e0 = 0;
    #pragma unroll
    for (int e = 1; e < 8; ++e) if (l8[e] > v0){ v0 = l8[e]; e0 = e; }
    float v1 = -3.402823466e38f; int e1 = 0;
    #pragma unroll
    for (int e = 0; e < 8; ++e) if (e != e0 && l8[e] > v1){ v1 = l8[e]; e1 = e; }
    float ex  = __expf(v1 - v0);
    float inv = 1.0f / (1.0f + ex);
    gate_ws[n0 + lane] = make_float4(__int_as_float(e0), __int_as_float(e1),
                                     inv, ex * inv);
  }
}

// ---------------- Kernel 2: out = (gate⊙ce) @ Bt^T.
// NEW: wave-private LDS transpose (double-buffered, NO __syncthreads anywhere) so
// each global store instruction covers 4 rows x 256B contiguous = full 128B lines
// (4 segments/instr instead of 16x64B). Stores stream; Btf register-resident.
__global__ __launch_bounds__(256, 4) void k2_gemm(
    const _Float16* __restrict__ Btf, const _Float16* __restrict__ ce16,
    const float4* __restrict__ gate_ws, float* __restrict__ out, int ntok)
{
  __shared__ float tbuf[4][2][16][68];      // per-wave double-buffered, +16B row pad
  const int tid = threadIdx.x, lane = tid & 63, wv = tid >> 6;
  const int c15 = lane & 15, kg = lane >> 4;
  const int bn = blockIdx.x & 3;          // o-chunk of 256
  const int tg = blockIdx.x >> 2;         // token group of 64
  const int o0w = bn * 256 + wv * 64;

  // Btf fragments for this wave's 64 o x 128 k: 16 coalesced 1KB loads, reused 4x
  half8 bt[4][4];
  #pragma unroll
  for (int nc = 0; nc < 4; ++nc){
    const int ot = bn * 16 + wv * 4 + nc;
    #pragma unroll
    for (int s = 0; s < 4; ++s)
      bt[nc][s] = *(const half8*)(Btf + ((size_t)(ot * 4 + s) * 64 + lane) * 8);
  }

  int tok = tg * 64 + c15;
  half8  ce_n = *(const half8*)(ce16 + (size_t)tok * 16 + (kg & 1) * 8);
  float4 gt_n = gate_ws[tok];

  #pragma unroll
  for (int i = 0; i < 4; ++i){
    half8 ce_c = ce_n;  float4 gt_c = gt_n;
    if (i < 3){
      const int tok2 = tg * 64 + (i + 1) * 16 + c15;
      ce_n = *(const half8*)(ce16 + (size_t)tok2 * 16 + (kg & 1) * 8);
      gt_n = gate_ws[tok2];
    }
    const int e0 = __float_as_int(gt_c.x), e1 = __float_as_int(gt_c.y);
    const int eb = kg >> 1;

    f32x4 acc[4] = {{0.f,0.f,0.f,0.f},{0.f,0.f,0.f,0.f},
                    {0.f,0.f,0.f,0.f},{0.f,0.f,0.f,0.f}};
    #pragma unroll
    for (int s = 0; s < 4; ++s){
      const int e = 2 * s + eb;           // expert of k-range [s*32+kg*8, +8)
      float sc = (e == e0) ? gt_c.z : ((e == e1) ? gt_c.w : 0.f);
      _Float16 sh = (_Float16)sc;
      half8 bfr;
      #pragma unroll
      for (int q = 0; q < 8; ++q) bfr[q] = ce_c[q] * sh;
      #pragma unroll
      for (int nc = 0; nc < 4; ++nc)
        acc[nc] = __builtin_amdgcn_mfma_f32_16x16x32_f16(bt[nc][s], bfr, acc[nc], 0, 0, 0);
    }
    // D[row = o-local = kg*4+v][col = token = c15] -> wave-private LDS transpose:
    // tbuf[wv][buf][token = c15][o-local = nc*16 + kg*4 + v]
    #pragma unroll
    for (int nc = 0; nc < 4; ++nc)
      *(f32x4*)&tbuf[wv][i & 1][c15][nc * 16 + kg * 4] = acc[nc];
    // same-wave DS pipe is in-order; compiler inserts lgkmcnt before these reads.
    // Dense store: instr p covers 4 token-rows x 256B contiguous (full lines).
    const int n0i = tg * 64 + i * 16;
    #pragma unroll
    for (int p = 0; p < 4; ++p){
      const int row = p * 4 + kg;         // token-local row
      float4 v = *(const float4*)&tbuf[wv][i & 1][row][c15 * 4];
      *(float4*)(out + (size_t)(n0i + row) * 1024 + o0w + c15 * 4) = v;
    }
  }
}

extern "C" void kernel_launch(void* const* d_in, const int* in_sizes, int n_in,
                              void* d_out, int out_size, void* d_ws, size_t ws_size,
                              hipStream_t stream)
{
  const float* x        = (const float*)d_in[0];
  const float* w_route  = (const float*)d_in[1];
  const float* compress = (const float*)d_in[2];
  const float* routed   = (const float*)d_in[3];
  float* out = (float*)d_out;

  const int ntok = in_sizes[0] / 1024;   // 16384 (B*T)
  char* ws = (char*)d_ws;
  _Float16* ce16    = (_Float16*)ws;                               // ntok*16 f16  (512 KB)
  float4*   gate_ws = (float4*)(ws + (size_t)ntok * 32);           // ntok*16 B    (256 KB)
  _Float16* Btf     = (_Float16*)(ws + (size_t)ntok * 48);         // 1024*128 f16 (256 KB)
  _Float16* A1f     = (_Float16*)(ws + (size_t)ntok * 48 + 262144);          // 32 KB
  _Float16* A2f     = (_Float16*)(ws + (size_t)ntok * 48 + 262144 + 32768);  // 32 KB

  k0_prep<<<48, 256, 0, stream>>>(routed, compress, w_route, Btf, A1f, A2f);
  k_main<<<ntok / 16, 256, 0, stream>>>(x, A1f, A2f, ce16, gate_ws, ntok);
  k2_gemm<<<(ntok / 64) * 4, 256, 0, stream>>>(Btf, ce16, gate_ws, out, ntok);
}

// Round 10
// 41.649 us; speedup vs baseline: 1.4118x; 1.0550x over previous
//
#include <hip/hip_runtime.h>

// TMoELayer: B=4,T=4096 -> N=16384 tokens, D_IN=1024, D_OUT=1024, E=8, TOP_K=2, R=16
// out[n][o] = sum_k (gate(n,e)*ce[n][r]) * routed[e][o][r], k = e*16+r
// Router logits via split-precision MFMA: W = Whi + Wlo/1024 (f16 pair),
// X = Xhi + Xlo (f16 pair) -> logit = Whi.Xhi + Whi.Xlo + (Wlo.Xhi + Wlo.Xlo)/1024.
// All operand tables are pre-layouted in FRAGMENT ORDER so every global load in the
// hot kernels is a contiguous 1KB wave-load (64 lanes x 16B), not 64 scattered pieces.
constexpr float SCALING = 2.0f;  // alpha/r = 32/16

typedef __attribute__((ext_vector_type(8))) _Float16 half8;
typedef __attribute__((ext_vector_type(4))) _Float16 half4;
typedef __attribute__((ext_vector_type(4))) float    f32x4;

// ---------------- Kernel 0: prep (fragment-order tables) — unchanged from R9
__global__ __launch_bounds__(256) void k0_prep(
    const float* __restrict__ routed, const float* __restrict__ compress,
    const float* __restrict__ w_route, _Float16* __restrict__ Btf,
    _Float16* __restrict__ A1f, _Float16* __restrict__ A2f)
{
  const int bid = blockIdx.x, tid = threadIdx.x;
  if (bid < 32){
    const int t = bid * 256 + tid;          // 0..8191, covers Btf idx pairs (2t,2t+1)
    const int l0  = (2 * t) & 63;           // even lane
    const int rem = (2 * t) >> 6;
    const int s = rem & 3, ot = rem >> 2;
    const int c15 = l0 & 15, kg = l0 >> 4;
    const int e  = 2 * s + (kg >> 1);
    const int r0 = (kg & 1) * 8;
    const float* src = routed + ((size_t)e * 1024 + ot * 16 + c15) * 16 + r0;
    float4 a = *(const float4*)(src);
    float4 b = *(const float4*)(src + 4);
    float4 c = *(const float4*)(src + 16);    // next o (c15+1)
    float4 d = *(const float4*)(src + 20);
    half8 h0, h1;
    h0[0]=(_Float16)a.x; h0[1]=(_Float16)a.y; h0[2]=(_Float16)a.z; h0[3]=(_Float16)a.w;
    h0[4]=(_Float16)b.x; h0[5]=(_Float16)b.y; h0[6]=(_Float16)b.z; h0[7]=(_Float16)b.w;
    h1[0]=(_Float16)c.x; h1[1]=(_Float16)c.y; h1[2]=(_Float16)c.z; h1[3]=(_Float16)c.w;
    h1[4]=(_Float16)d.x; h1[5]=(_Float16)d.y; h1[6]=(_Float16)d.z; h1[7]=(_Float16)d.w;
    *(half8*)(Btf + (size_t)t * 16)     = h0;
    *(half8*)(Btf + (size_t)t * 16 + 8) = h1;
  } else if (bid < 40){
    const int t2 = (bid - 32) * 256 + tid;  // 0..2047 -> A2f fragment t2
    const int l = t2 & 63, s = (t2 >> 6) & 7, wq = t2 >> 9;
    const int c15 = l & 15, kg = l >> 4;
    const float* src = compress + (size_t)c15 * 1024 + wq * 256 + s * 32 + kg * 8;
    float4 a = *(const float4*)(src);
    float4 b = *(const float4*)(src + 4);
    half8 h;
    h[0]=(_Float16)(SCALING*a.x); h[1]=(_Float16)(SCALING*a.y);
    h[2]=(_Float16)(SCALING*a.z); h[3]=(_Float16)(SCALING*a.w);
    h[4]=(_Float16)(SCALING*b.x); h[5]=(_Float16)(SCALING*b.y);
    h[6]=(_Float16)(SCALING*b.z); h[7]=(_Float16)(SCALING*b.w);
    *(half8*)(A2f + (size_t)t2 * 8) = h;
  } else {
    const int t3 = (bid - 40) * 256 + tid;  // 0..2047 -> A1f fragment t3
    const int l = t3 & 63, s = (t3 >> 6) & 7, wq = t3 >> 9;
    const int c15 = l & 15, kg = l >> 4;
    const int row = (c15 < 8) ? c15 : (c15 - 8);
    const float* src = w_route + (size_t)row * 1024 + wq * 256 + s * 32 + kg * 8;
    float4 a = *(const float4*)(src);
    float4 b = *(const float4*)(src + 4);
    float ws[8] = {a.x, a.y, a.z, a.w, b.x, b.y, b.z, b.w};
    half8 h;
    #pragma unroll
    for (int j = 0; j < 8; ++j){
      _Float16 hi = (_Float16)ws[j];
      h[j] = (c15 < 8) ? hi : (_Float16)((ws[j] - (float)hi) * 1024.f);
    }
    *(half8*)(A1f + (size_t)t3 * 8) = h;
  }
}

// ---------------- Kernel 1: all-MFMA router + ce. NOW 8-token tiles:
// LDS 45 KB -> 3 blocks/CU (was 78 KB -> 2), grid 2048 -> more concurrent
// staging streams per CU (duty-cycle fix). MFMA B-cols 8..15 unused.
// A-fragments hoisted to registers BEFORE the staging barrier (L2 latency
// overlapped with x staging).
__global__ __launch_bounds__(256, 3) void k_main(
    const float* __restrict__ x, const _Float16* __restrict__ A1f,
    const _Float16* __restrict__ A2f, _Float16* __restrict__ ce16,
    float4* __restrict__ gate_ws, int ntok)
{
  __shared__ _Float16 xh[8 * 1032];         // 16.5 KB, row pitch 1032 halfs
  __shared__ _Float16 xl[8 * 1032];         // 16.5 KB
  __shared__ f32x4 p1[4][64], p2[4][64], p3[4][64];   // 12 KB
  const int tid = threadIdx.x, lane = tid & 63, wv = tid >> 6;
  const int c15 = lane & 15, kg = lane >> 4;
  const int n0 = blockIdx.x * 8;

  // ---- hoist A fragments (L2-resident tables): 16 x half8 = 64 VGPR
  half8 a1f[8], a2f[8];
  #pragma unroll
  for (int s = 0; s < 8; ++s){
    a1f[s] = *(const half8*)(A1f + ((size_t)(wv * 8 + s) * 64 + lane) * 8);
    a2f[s] = *(const half8*)(A2f + ((size_t)(wv * 8 + s) * 64 + lane) * 8);
  }

  // ---- stage: wave wv loads rows wv*2, wv*2+1 contiguously, cvt hi/lo, LDS
  float4 xv[8];
  #pragma unroll
  for (int u = 0; u < 8; ++u){
    const int rr = u >> 2, qt = u & 3;
    xv[u] = *(const float4*)(x + (size_t)(n0 + wv * 2 + rr) * 1024 + qt * 256 + lane * 4);
  }
  #pragma unroll
  for (int u = 0; u < 8; ++u){
    const int rr = u >> 2, qt = u & 3;
    float xs[4] = {xv[u].x, xv[u].y, xv[u].z, xv[u].w};
    half4 hi, lo;
    #pragma unroll
    for (int q = 0; q < 4; ++q){
      _Float16 h = (_Float16)xs[q];
      hi[q] = h;
      lo[q] = (_Float16)(xs[q] - (float)h);
    }
    const int ho = (wv * 2 + rr) * 1032 + qt * 256 + lane * 4;
    *(half4*)&xh[ho] = hi;
    *(half4*)&xl[ho] = lo;
  }
  __syncthreads();

  // ---- MFMA: wave wv does K-quarter wv. 3 streams x 8 steps.
  // B cols 0..7 = tokens; cols 8..15 read row (c15&7) (broadcast, discarded).
  f32x4 acc1 = {0.f,0.f,0.f,0.f};   // [Whi;Wlo] * Xhi
  f32x4 acc3 = {0.f,0.f,0.f,0.f};   // [Whi;Wlo] * Xlo
  f32x4 acc2 = {0.f,0.f,0.f,0.f};   // (2*compress) * Xhi
  #pragma unroll
  for (int s = 0; s < 8; ++s){
    const int xo = (c15 & 7) * 1032 + wv * 256 + s * 32 + kg * 8;
    half8 bhi = *(const half8*)&xh[xo];
    half8 blo = *(const half8*)&xl[xo];
    acc1 = __builtin_amdgcn_mfma_f32_16x16x32_f16(a1f[s], bhi, acc1, 0, 0, 0);
    acc3 = __builtin_amdgcn_mfma_f32_16x16x32_f16(a1f[s], blo, acc3, 0, 0, 0);
    acc2 = __builtin_amdgcn_mfma_f32_16x16x32_f16(a2f[s], bhi, acc2, 0, 0, 0);
  }
  p1[wv][lane] = acc1;  p3[wv][lane] = acc3;  p2[wv][lane] = acc2;
  __syncthreads();
  if (wv != 0) return;

  f32x4 L = (p1[0][lane] + p1[1][lane]) + (p1[2][lane] + p1[3][lane]);
  f32x4 X = (p3[0][lane] + p3[1][lane]) + (p3[2][lane] + p3[3][lane]);
  f32x4 C = (p2[0][lane] + p2[1][lane]) + (p2[2][lane] + p2[3][lane]);

  // ce store: D row = r = kg*4+v, col = token = c15 (only c15<8 valid)
  if (c15 < 8){
    half4 hce;
    hce[0]=(_Float16)C[0]; hce[1]=(_Float16)C[1];
    hce[2]=(_Float16)C[2]; hce[3]=(_Float16)C[3];
    *(half4*)(ce16 + (size_t)(n0 + c15) * 16 + kg * 4) = hce;
  }

  // logits: rows 0..7 (kg 0/1) pick up Wlo terms from rows 8..15 (lane+32)
  float lg[4];
  #pragma unroll
  for (int v = 0; v < 4; ++v){
    float wlo_xhi = __shfl_xor(L[v], 32, 64);
    float wlo_xlo = __shfl_xor(X[v], 32, 64);
    lg[v] = L[v] + X[v] + (wlo_xhi + wlo_xlo) * (1.0f / 1024.0f);
  }
  float l8[8];
  #pragma unroll
  for (int v = 0; v < 4; ++v){
    l8[v]     = lg[v];
    l8[4 + v] = __shfl_xor(lg[v], 16, 64);
  }
  if (lane < 8 && n0 + lane < ntok){
    float v0 = l8[0]; int e0 = 0;
    #pragma unroll
    for (int e = 1; e < 8; ++e) if (l8[e] > v0){ v0 = l8[e]; e0 = e; }
    float v1 = -3.402823466e38f; int e1 = 0;
    #pragma unroll
    for (int e = 0; e < 8; ++e) if (e != e0 && l8[e] > v1){ v1 = l8[e]; e1 = e; }
    float ex  = __expf(v1 - v0);
    float inv = 1.0f / (1.0f + ex);
    gate_ws[n0 + lane] = make_float4(__int_as_float(e0), __int_as_float(e1),
                                     inv, ex * inv);
  }
}

// ---------------- Kernel 2: out = (gate⊙ce) @ Bt^T — unchanged from R9
__global__ __launch_bounds__(256, 4) void k2_gemm(
    const _Float16* __restrict__ Btf, const _Float16* __restrict__ ce16,
    const float4* __restrict__ gate_ws, float* __restrict__ out, int ntok)
{
  __shared__ float tbuf[4][2][16][68];      // per-wave double-buffered, +16B row pad
  const int tid = threadIdx.x, lane = tid & 63, wv = tid >> 6;
  const int c15 = lane & 15, kg = lane >> 4;
  const int bn = blockIdx.x & 3;          // o-chunk of 256
  const int tg = blockIdx.x >> 2;         // token group of 64
  const int o0w = bn * 256 + wv * 64;

  half8 bt[4][4];
  #pragma unroll
  for (int nc = 0; nc < 4; ++nc){
    const int ot = bn * 16 + wv * 4 + nc;
    #pragma unroll
    for (int s = 0; s < 4; ++s)
      bt[nc][s] = *(const half8*)(Btf + ((size_t)(ot * 4 + s) * 64 + lane) * 8);
  }

  int tok = tg * 64 + c15;
  half8  ce_n = *(const half8*)(ce16 + (size_t)tok * 16 + (kg & 1) * 8);
  float4 gt_n = gate_ws[tok];

  #pragma unroll
  for (int i = 0; i < 4; ++i){
    half8 ce_c = ce_n;  float4 gt_c = gt_n;
    if (i < 3){
      const int tok2 = tg * 64 + (i + 1) * 16 + c15;
      ce_n = *(const half8*)(ce16 + (size_t)tok2 * 16 + (kg & 1) * 8);
      gt_n = gate_ws[tok2];
    }
    const int e0 = __float_as_int(gt_c.x), e1 = __float_as_int(gt_c.y);
    const int eb = kg >> 1;

    f32x4 acc[4] = {{0.f,0.f,0.f,0.f},{0.f,0.f,0.f,0.f},
                    {0.f,0.f,0.f,0.f},{0.f,0.f,0.f,0.f}};
    #pragma unroll
    for (int s = 0; s < 4; ++s){
      const int e = 2 * s + eb;           // expert of k-range [s*32+kg*8, +8)
      float sc = (e == e0) ? gt_c.z : ((e == e1) ? gt_c.w : 0.f);
      _Float16 sh = (_Float16)sc;
      half8 bfr;
      #pragma unroll
      for (int q = 0; q < 8; ++q) bfr[q] = ce_c[q] * sh;
      #pragma unroll
      for (int nc = 0; nc < 4; ++nc)
        acc[nc] = __builtin_amdgcn_mfma_f32_16x16x32_f16(bt[nc][s], bfr, acc[nc], 0, 0, 0);
    }
    #pragma unroll
    for (int nc = 0; nc < 4; ++nc)
      *(f32x4*)&tbuf[wv][i & 1][c15][nc * 16 + kg * 4] = acc[nc];
    const int n0i = tg * 64 + i * 16;
    #pragma unroll
    for (int p = 0; p < 4; ++p){
      const int row = p * 4 + kg;         // token-local row
      float4 v = *(const float4*)&tbuf[wv][i & 1][row][c15 * 4];
      *(float4*)(out + (size_t)(n0i + row) * 1024 + o0w + c15 * 4) = v;
    }
  }
}

extern "C" void kernel_launch(void* const* d_in, const int* in_sizes, int n_in,
                              void* d_out, int out_size, void* d_ws, size_t ws_size,
                              hipStream_t stream)
{
  const float* x        = (const float*)d_in[0];
  const float* w_route  = (const float*)d_in[1];
  const float* compress = (const float*)d_in[2];
  const float* routed   = (const float*)d_in[3];
  float* out = (float*)d_out;

  const int ntok = in_sizes[0] / 1024;   // 16384 (B*T)
  char* ws = (char*)d_ws;
  _Float16* ce16    = (_Float16*)ws;                               // ntok*16 f16  (512 KB)
  float4*   gate_ws = (float4*)(ws + (size_t)ntok * 32);           // ntok*16 B    (256 KB)
  _Float16* Btf     = (_Float16*)(ws + (size_t)ntok * 48);         // 1024*128 f16 (256 KB)
  _Float16* A1f     = (_Float16*)(ws + (size_t)ntok * 48 + 262144);          // 32 KB
  _Float16* A2f     = (_Float16*)(ws + (size_t)ntok * 48 + 262144 + 32768);  // 32 KB

  k0_prep<<<48, 256, 0, stream>>>(routed, compress, w_route, Btf, A1f, A2f);
  k_main<<<ntok / 8, 256, 0, stream>>>(x, A1f, A2f, ce16, gate_ws, ntok);
  k2_gemm<<<(ntok / 64) * 4, 256, 0, stream>>>(Btf, ce16, gate_ws, out, ntok);
}